// Round 11
// baseline (131.117 us; speedup 1.0000x reference)
//
#include <hip/hip_runtime.h>
#include <hip/hip_cooperative_groups.h>

namespace cg = cooperative_groups;

// B=16,S=38 -> ROWS=608; D=1792; H=4, DK=448; NP=128; INF=768
typedef __attribute__((ext_vector_type(8))) short short8v;   // 8 bf16 (4 VGPR)
typedef __attribute__((ext_vector_type(4))) float f32x4;     // MFMA acc

#define APL 5120              // A plane stride (halfwords): 128*40
#define BPL 5184              // B plane stride: 128*40 + 8*8 (group pad)
#define BBASE 15360           // B region start (halfwords): 3*APL
#define MAXGRID 448

struct MA {
    const float *X, *proto, *Wq, *bq, *Wk, *bk, *Wv, *bv, *Wo, *bo, *Wfc, *bfc, *Wqa, *bqa;
    float *P, *Kp, *W2b, *sbias, *WbigB, *WoQ, *WvWoQ, *cv, *const2, *out;
};

__device__ __forceinline__ float wave_sum(float v) {
    #pragma unroll
    for (int off = 32; off; off >>= 1) v += __shfl_down(v, off);
    return v;
}

// out[m*2+c] = A[m,:] @ W[:,c]  (W row-major [K][2]); K % 256 == 0
__device__ __forceinline__ void colvec2_unit(
    const float* __restrict__ A, int lda, const float* __restrict__ W,
    float* __restrict__ out, int K, int m, int lane)
{
    const float4* a = (const float4*)(A + (long)m * lda);
    float a0 = 0.f, a1 = 0.f;
    for (int i = 0; i < K / 256; ++i) {
        const int d4 = lane + 64 * i;
        float4 xv = a[d4];
        const float4* w = (const float4*)(W + (long)d4 * 8);
        float4 w0 = w[0], w1 = w[1];
        a0 += xv.x*w0.x + xv.y*w0.z + xv.z*w1.x + xv.w*w1.z;
        a1 += xv.x*w0.y + xv.y*w0.w + xv.z*w1.y + xv.w*w1.w;
    }
    a0 = wave_sum(a0); a1 = wave_sum(a1);
    if (lane == 0) { out[m * 2 + 0] = a0; out[m * 2 + 1] = a1; }
}

__device__ __forceinline__ void sbias_unit(
    const float* __restrict__ bq, const float* __restrict__ Kp,
    float* __restrict__ sb, int unit, int lane)
{
    const int h = unit >> 7, p = unit & 127;
    const float* kr = Kp + (long)p * 1792 + h * 448;
    const float* bh = bq + h * 448;
    float s = 0.f;
    #pragma unroll
    for (int i = 0; i < 7; ++i) s = fmaf(bh[lane + 64 * i], kr[lane + 64 * i], s);
    s = wave_sum(s);
    if (lane == 0) sb[unit] = s;
}

__device__ __forceinline__ void wvwoq_unit(
    const float* __restrict__ Wv, const float* __restrict__ WoQ,
    float* __restrict__ out, int d, int h, int lane)
{
    const float* wr = Wv + (long)d * 1792 + h * 448;
    const float* wq = WoQ + h * 448 * 2;
    float s0 = 0.f, s1 = 0.f;
    #pragma unroll
    for (int i = 0; i < 7; ++i) {
        const int j = lane + 64 * i;
        const float v = wr[j];
        s0 = fmaf(v, wq[j * 2 + 0], s0);
        s1 = fmaf(v, wq[j * 2 + 1], s1);
    }
    s0 = wave_sum(s0); s1 = wave_sum(s1);
    if (lane == 0) {
        out[((long)h * 1792 + d) * 2 + 0] = s0;
        out[((long)h * 1792 + d) * 2 + 1] = s1;
    }
}

__device__ __forceinline__ void bias_unit(
    const float* __restrict__ bv, const float* __restrict__ WoQ,
    const float* __restrict__ bfc, const float* __restrict__ Wqa,
    const float* __restrict__ bo, const float* __restrict__ WfbQ,
    const float* __restrict__ bqa,
    float* __restrict__ cv, float* __restrict__ const2, int unit, int lane)
{
    float s0 = 0.f, s1 = 0.f;
    if (unit < 4) {
        const int h = unit;
        #pragma unroll
        for (int i = 0; i < 7; ++i) {
            const int j = h * 448 + lane + 64 * i;
            const float v = bv[j];
            s0 = fmaf(v, WoQ[j * 2 + 0], s0);
            s1 = fmaf(v, WoQ[j * 2 + 1], s1);
        }
    } else {
        for (int k = lane; k < 1792; k += 64) {
            if (k < 768) {
                s0 = fmaf(bfc[k], Wqa[k * 2 + 0], s0);
                s1 = fmaf(bfc[k], Wqa[k * 2 + 1], s1);
            }
            s0 = fmaf(bo[k], WfbQ[k * 2 + 0], s0);
            s1 = fmaf(bo[k], WfbQ[k * 2 + 1], s1);
        }
    }
    s0 = wave_sum(s0); s1 = wave_sum(s1);
    if (lane == 0) {
        if (unit < 4) { cv[unit * 2 + 0] = s0; cv[unit * 2 + 1] = s1; }
        else          { const2[0] = s0 + bqa[0]; const2[1] = s1 + bqa[1]; }
    }
}

// fp32 -> 3 bf16 limbs (truncation; residue <= 2^-24 |f|)
__device__ __forceinline__ void split3(float f, unsigned& h, unsigned& m, unsigned& l) {
    unsigned u = __float_as_uint(f);
    h = u >> 16;
    float r1 = f - __uint_as_float(u & 0xFFFF0000u);
    unsigned u1 = __float_as_uint(r1);
    m = u1 >> 16;
    float r2 = r1 - __uint_as_float(u1 & 0xFFFF0000u);
    l = __float_as_uint(r2) >> 16;
}

__device__ __forceinline__ int BROWF(int n) { return n * 40 + (n >> 4) * 8; }

// bf16x3 MFMA GEMM tile (identical math/layout to round-9 passing kernel).
template<bool TRANSB>
__device__ void gemm_tile(unsigned short* sh,
    const float* __restrict__ A, int lda,
    const float* __restrict__ B, int ldb,
    float* __restrict__ Cslab, int M, int N,
    int rowBase, int colBase, int kbeg, int nsteps)
{
    const int tid = threadIdx.x;
    const int lane = tid & 63, wave = tid >> 6;
    const int g = lane >> 4, c = lane & 15;
    const int wm = (wave >> 1) * 64, wn = (wave & 1) * 64;

    const int s_arow = tid >> 1, s_ak = (tid & 1) * 16;
    const int s_bk = tid >> 3,  s_bn = (tid & 7) * 16;
    const int s_tn = tid >> 1,  s_tk = (tid & 1) * 16;

    const bool aok = (rowBase + s_arow) < M;
    const float* Arow = A + (long)(rowBase + s_arow) * lda;

    float4 ra[4], rb[4];
    auto loadRaw = [&](int ks) {
        const int k0 = kbeg + ks * 32;
        #pragma unroll
        for (int i = 0; i < 4; ++i)
            ra[i] = aok ? *(const float4*)&Arow[k0 + s_ak + i * 4]
                        : make_float4(0.f, 0.f, 0.f, 0.f);
        if (!TRANSB) {
            const float* bp = B + (long)(k0 + s_bk) * ldb + colBase + s_bn;
            #pragma unroll
            for (int i = 0; i < 4; ++i) rb[i] = *(const float4*)&bp[i * 4];
        } else {
            const float* bp = B + (long)(colBase + s_tn) * ldb + k0 + s_tk;
            #pragma unroll
            for (int i = 0; i < 4; ++i) rb[i] = *(const float4*)&bp[i * 4];
        }
    };

    auto stageWrite = [&]() {
        {
            const float* f = (const float*)ra;
            unsigned ph[8], pm[8], pl[8];
            #pragma unroll
            for (int j = 0; j < 8; ++j) {
                unsigned h0, m0, l0, h1, m1, l1;
                split3(f[2*j], h0, m0, l0);
                split3(f[2*j+1], h1, m1, l1);
                ph[j] = h0 | (h1 << 16);
                pm[j] = m0 | (m1 << 16);
                pl[j] = l0 | (l1 << 16);
            }
            const int base = s_arow * 40 + s_ak;
            unsigned short* ap = sh;
            *(uint4*)&ap[0*APL + base]     = make_uint4(ph[0],ph[1],ph[2],ph[3]);
            *(uint4*)&ap[0*APL + base + 8] = make_uint4(ph[4],ph[5],ph[6],ph[7]);
            *(uint4*)&ap[1*APL + base]     = make_uint4(pm[0],pm[1],pm[2],pm[3]);
            *(uint4*)&ap[1*APL + base + 8] = make_uint4(pm[4],pm[5],pm[6],pm[7]);
            *(uint4*)&ap[2*APL + base]     = make_uint4(pl[0],pl[1],pl[2],pl[3]);
            *(uint4*)&ap[2*APL + base + 8] = make_uint4(pl[4],pl[5],pl[6],pl[7]);
        }
        unsigned short* bp = sh + BBASE;
        if (!TRANSB) {
            const float* f = (const float*)rb;
            #pragma unroll
            for (int j = 0; j < 16; ++j) {
                unsigned h, m, l;
                split3(f[j], h, m, l);
                const int ad = BROWF(s_bn + j) + s_bk;
                bp[0*BPL + ad] = (unsigned short)h;
                bp[1*BPL + ad] = (unsigned short)m;
                bp[2*BPL + ad] = (unsigned short)l;
            }
        } else {
            const float* f = (const float*)rb;
            unsigned ph[8], pm[8], pl[8];
            #pragma unroll
            for (int j = 0; j < 8; ++j) {
                unsigned h0, m0, l0, h1, m1, l1;
                split3(f[2*j], h0, m0, l0);
                split3(f[2*j+1], h1, m1, l1);
                ph[j] = h0 | (h1 << 16);
                pm[j] = m0 | (m1 << 16);
                pl[j] = l0 | (l1 << 16);
            }
            const int base = BROWF(s_tn) + s_tk;
            *(uint4*)&bp[0*BPL + base]     = make_uint4(ph[0],ph[1],ph[2],ph[3]);
            *(uint4*)&bp[0*BPL + base + 8] = make_uint4(ph[4],ph[5],ph[6],ph[7]);
            *(uint4*)&bp[1*BPL + base]     = make_uint4(pm[0],pm[1],pm[2],pm[3]);
            *(uint4*)&bp[1*BPL + base + 8] = make_uint4(pm[4],pm[5],pm[6],pm[7]);
            *(uint4*)&bp[2*BPL + base]     = make_uint4(pl[0],pl[1],pl[2],pl[3]);
            *(uint4*)&bp[2*BPL + base + 8] = make_uint4(pl[4],pl[5],pl[6],pl[7]);
        }
    };

    f32x4 acc[4][4];
    #pragma unroll
    for (int i = 0; i < 4; ++i)
        #pragma unroll
        for (int j = 0; j < 4; ++j)
            acc[i][j] = (f32x4){0.f, 0.f, 0.f, 0.f};

    loadRaw(0);
    for (int s = 0; s < nsteps; ++s) {
        __syncthreads();
        stageWrite();
        if (s + 1 < nsteps) loadRaw(s + 1);
        __syncthreads();

        const unsigned short* ap = sh;
        const unsigned short* bp = sh + BBASE;
        short8v bfr[3][4];
        #pragma unroll
        for (int ni = 0; ni < 4; ++ni) {
            const int hwb = (wn + 16*ni + c) * 40 + ((wn + 16*ni) >> 4) * 8 + 8 * g;
            bfr[0][ni] = *(const short8v*)&bp[0*BPL + hwb];
            bfr[1][ni] = *(const short8v*)&bp[1*BPL + hwb];
            bfr[2][ni] = *(const short8v*)&bp[2*BPL + hwb];
        }
        #pragma unroll
        for (int mi = 0; mi < 4; ++mi) {
            const int hwa = (wm + 16*mi + c) * 40 + 8 * g;
            short8v ah = *(const short8v*)&ap[0*APL + hwa];
            short8v am = *(const short8v*)&ap[1*APL + hwa];
            short8v al = *(const short8v*)&ap[2*APL + hwa];
            #pragma unroll
            for (int ni = 0; ni < 4; ++ni) {
                f32x4 t = acc[mi][ni];
                t = __builtin_amdgcn_mfma_f32_16x16x32_bf16(ah, bfr[0][ni], t, 0, 0, 0);
                t = __builtin_amdgcn_mfma_f32_16x16x32_bf16(ah, bfr[1][ni], t, 0, 0, 0);
                t = __builtin_amdgcn_mfma_f32_16x16x32_bf16(am, bfr[0][ni], t, 0, 0, 0);
                t = __builtin_amdgcn_mfma_f32_16x16x32_bf16(ah, bfr[2][ni], t, 0, 0, 0);
                t = __builtin_amdgcn_mfma_f32_16x16x32_bf16(am, bfr[1][ni], t, 0, 0, 0);
                t = __builtin_amdgcn_mfma_f32_16x16x32_bf16(al, bfr[0][ni], t, 0, 0, 0);
                acc[mi][ni] = t;
            }
        }
    }

    #pragma unroll
    for (int mi = 0; mi < 4; ++mi)
        #pragma unroll
        for (int ni = 0; ni < 4; ++ni) {
            const int col = colBase + wn + 16*ni + c;
            #pragma unroll
            for (int r = 0; r < 4; ++r) {
                const int row = rowBase + wm + 16*mi + 4*g + r;
                if (row < M) Cslab[(long)row * N + col] = acc[mi][ni][r];
            }
        }
}

// ---- phases (grid-stride; work mapping identical to passing rounds) ----

__device__ void phaseA(const MA& a, unsigned short* sh) {
    const int lane = threadIdx.x & 63, wave = threadIdx.x >> 6;
    for (int w = blockIdx.x; w < 196 + 448; w += gridDim.x) {
        if (w < 196) {
            const int kb = w % 14, tx = w / 14;
            gemm_tile<false>(sh, a.proto, 1792, a.Wk, 1792,
                             a.P + (long)kb * 229376, 128, 1792,
                             0, tx * 128, kb * 128, 4);
        } else {
            const int u = (w - 196) * 4 + wave;   // 0..1791: WfbQ = Wfc_bot @ Wqa
            if (u < 1792) colvec2_unit(a.Wfc + 1792L * 768, 768, a.Wqa,
                                       a.WbigB + 3584, 768, u, lane);
        }
    }
}

__device__ void phaseB(const MA& a) {
    const int lane = threadIdx.x & 63, wave = threadIdx.x >> 6;
    for (int w = blockIdx.x; w < 224 + 448; w += gridDim.x) {
        if (w < 224) {
            const long i0 = (long)w * 1024 + threadIdx.x * 4;
            float4 s = make_float4(0.f, 0.f, 0.f, 0.f);
            for (int z = 0; z < 14; ++z) {
                float4 v = *(const float4*)&a.P[z * 229376L + i0];
                s.x += v.x; s.y += v.y; s.z += v.z; s.w += v.w;
            }
            const int col = (int)(i0 % 1792);
            float4 b4 = *(const float4*)&a.bk[col];
            s.x += b4.x; s.y += b4.y; s.z += b4.z; s.w += b4.w;
            *(float4*)&a.Kp[i0] = s;
        } else {
            const int u = (w - 224) * 4 + wave;   // WoQ = Wo @ WfbQ
            if (u < 1792) colvec2_unit(a.Wo, 1792, a.WbigB + 3584, a.WoQ, 1792, u, lane);
        }
    }
}

__device__ void phaseC(const MA& a, unsigned short* sh) {
    const int lane = threadIdx.x & 63, wave = threadIdx.x >> 6;
    for (int w = blockIdx.x; w < 1136; w += gridDim.x) {
        if (w < 112) {
            const int kb = w & 1, r = w >> 1, bb = r & 3, ty = r >> 2;
            gemm_tile<true>(sh, a.Wq + 448 * bb, 1792, a.Kp + 448 * bb, 1792,
                            a.P + (long)(kb * 4 + bb) * 229376, 1792, 128,
                            ty * 128, 0, kb * 224, 7);
        } else if (w < 240) {
            const int u = (w - 112) * 4 + wave;
            if (u < 512) sbias_unit(a.bq, a.Kp, a.sbias, u, lane);
        } else {
            const int u = (w - 240) * 4 + wave;   // wvwoq units 0..3583 (h=0,1)
            if (u < 3584) wvwoq_unit(a.Wv, a.WoQ, a.WvWoQ, u % 1792, u / 1792, lane);
        }
    }
}

__device__ void phaseD(const MA& a) {
    const int lane = threadIdx.x & 63, wave = threadIdx.x >> 6;
    for (int w = blockIdx.x; w < 1794; w += gridDim.x) {
        if (w < 896) {
            const long i0 = (long)w * 1024 + threadIdx.x * 4;
            float4 v0 = *(const float4*)&a.P[i0];
            float4 v1 = *(const float4*)&a.P[917504L + i0];
            *(float4*)&a.W2b[i0] = make_float4(v0.x + v1.x, v0.y + v1.y,
                                               v0.z + v1.z, v0.w + v1.w);
        } else if (w < 1792) {
            const int u = (w - 896) * 4 + wave;   // wvwoq units 3584..7167 (h=2,3)
            if (u < 3584) {
                const int unit = 3584 + u;
                wvwoq_unit(a.Wv, a.WoQ, a.WvWoQ, unit % 1792, unit / 1792, lane);
            }
        } else {
            const int u = (w - 1792) * 4 + wave;
            if (u < 5) bias_unit(a.bv, a.WoQ, a.bfc, a.Wqa, a.bo, a.WbigB + 3584,
                                 a.bqa, a.cv, a.const2, u, lane);
        }
    }
}

__device__ void phaseE(const MA& a, unsigned short* sh) {
    const int lane = threadIdx.x & 63, wave = threadIdx.x >> 6;
    for (int w = blockIdx.x; w < 280 + 448; w += gridDim.x) {
        if (w < 280) {
            const int kb = w % 14, r = w / 14, bb = r & 3, ty = r >> 2;   // ty 0..4
            gemm_tile<false>(sh, a.X, 1792, a.W2b + 229376L * bb, 128,
                             a.P + (long)(kb * 4 + bb) * 77824, 608, 128,
                             ty * 128, 0, kb * 128, 4);
        } else {
            const int u = (w - 280) * 4 + wave;   // Wbig = Wfc_top @ Wqa
            if (u < 1792) colvec2_unit(a.Wfc, 768, a.Wqa, a.WbigB, 768, u, lane);
        }
    }
}

__device__ void phaseF(const MA& a) {
    const int lane = threadIdx.x & 63, wave = threadIdx.x >> 6;
    for (int w = blockIdx.x; w < 152; w += gridDim.x) {
        const int row = w * 4 + wave;

        int sel[4];
        #pragma unroll
        for (int h = 0; h < 4; ++h) {
            float s0 = a.sbias[h * 128 + lane];
            float s1 = a.sbias[h * 128 + lane + 64];
            #pragma unroll 2
            for (int z = 0; z < 14; ++z) {
                const long base = ((long)(z * 4 + h) * 608 + row) * 128;
                s0 += a.P[base + lane];
                s1 += a.P[base + lane + 64];
            }
            float best = s0; int bi = lane;
            if (s1 > best) { best = s1; bi = lane + 64; }
            #pragma unroll
            for (int off = 32; off; off >>= 1) {
                float ov = __shfl_down(best, off);
                int   oi = __shfl_down(bi, off);
                if (ov > best || (ov == best && oi < bi)) { best = ov; bi = oi; }
            }
            sel[h] = __shfl(bi, 0);
        }

        float a0 = 0.f, a1 = 0.f;
        auto dot2 = [&](const float* av_, const float* w_) {
            const float4* av = (const float4*)av_;
            #pragma unroll
            for (int i = 0; i < 7; ++i) {
                const int d4 = lane + 64 * i;
                float4 xv = av[d4];
                const float4* wp = (const float4*)(w_ + (long)d4 * 8);
                float4 w0 = wp[0], w1 = wp[1];
                a0 += xv.x*w0.x + xv.y*w0.z + xv.z*w1.x + xv.w*w1.z;
                a1 += xv.x*w0.y + xv.y*w0.w + xv.z*w1.y + xv.w*w1.w;
            }
        };
        dot2(a.X + (long)row * 1792, a.WbigB);
        #pragma unroll
        for (int h = 0; h < 4; ++h)
            dot2(a.proto + (long)sel[h] * 1792, a.WvWoQ + (long)h * 3584);

        a0 = wave_sum(a0); a1 = wave_sum(a1);
        if (lane == 0) {
            a.out[row * 2 + 0] = a0 + a.const2[0] + a.cv[0] + a.cv[2] + a.cv[4] + a.cv[6];
            a.out[row * 2 + 1] = a1 + a.const2[1] + a.cv[1] + a.cv[3] + a.cv[5] + a.cv[7];
        }
    }
}

// ---- single cooperative kernel; (256,2): min 2 waves/EU -> VGPR<=256 -> 2 blocks/CU ----
__global__ __launch_bounds__(256, 2) void mega(MA a) {
    __shared__ unsigned short sh[30912];
    cg::grid_group grid = cg::this_grid();
    phaseA(a, sh);  grid.sync();
    phaseB(a);      grid.sync();
    phaseC(a, sh);  grid.sync();
    phaseD(a);      grid.sync();
    phaseE(a, sh);  grid.sync();
    phaseF(a);
}

// ---- fallback: same phases as 6 ordinary launches ----
__global__ __launch_bounds__(256) void phA_k(MA a) { __shared__ unsigned short sh[30912]; phaseA(a, sh); }
__global__ __launch_bounds__(256) void phB_k(MA a) { phaseB(a); }
__global__ __launch_bounds__(256) void phC_k(MA a) { __shared__ unsigned short sh[30912]; phaseC(a, sh); }
__global__ __launch_bounds__(256) void phD_k(MA a) { phaseD(a); }
__global__ __launch_bounds__(256) void phE_k(MA a) { __shared__ unsigned short sh[30912]; phaseE(a, sh); }
__global__ __launch_bounds__(256) void phF_k(MA a) { phaseF(a); }

extern "C" void kernel_launch(void* const* d_in, const int* in_sizes, int n_in,
                              void* d_out, int out_size, void* d_ws, size_t ws_size,
                              hipStream_t stream)
{
    MA a;
    a.X     = (const float*)d_in[0];
    a.proto = (const float*)d_in[1];
    a.Wq  = (const float*)d_in[3];
    a.bq  = (const float*)d_in[4];
    a.Wk  = (const float*)d_in[5];
    a.bk  = (const float*)d_in[6];
    a.Wv  = (const float*)d_in[7];
    a.bv  = (const float*)d_in[8];
    a.Wo  = (const float*)d_in[9];
    a.bo  = (const float*)d_in[10];
    a.Wfc = (const float*)d_in[11];
    a.bfc = (const float*)d_in[12];
    a.Wqa = (const float*)d_in[13];
    a.bqa = (const float*)d_in[14];
    a.out = (float*)d_out;

    float* ws = (float*)d_ws;
    a.P      = ws;                      // max 4,358,144 floats (Sc: 56 slabs x 77824)
    a.Kp     = a.P + 4358144;           // 229,376  [128][1792]
    a.W2b    = a.Kp + 229376;           // 917,504  [4][1792][128]
    a.sbias  = a.W2b + 917504;          // 512
    a.WbigB  = a.sbias + 512;           // 7,168    [3584][2] (top=Wbig, bottom=WfbQ)
    a.WoQ    = a.WbigB + 7168;          // 3,584
    a.WvWoQ  = a.WoQ + 3584;            // 14,336
    a.cv     = a.WvWoQ + 14336;         // 8
    a.const2 = a.cv + 8;                // 2 (+6 pad)

    // Size the cooperative grid from a runtime occupancy query (deadlock-proof):
    int maxB = 0;
    hipError_t qe = hipOccupancyMaxActiveBlocksPerMultiprocessor(&maxB, mega, 256, 0);
    bool coopOK = (qe == hipSuccess && maxB >= 1);
    if (coopOK) {
        int grid = maxB * 256;                 // 256 CUs on MI355X
        if (grid > MAXGRID) grid = MAXGRID;
        void* params[] = { (void*)&a };
        hipError_t e = hipLaunchCooperativeKernel((const void*)mega, dim3(grid), dim3(256),
                                                  params, 0, stream);
        if (e == hipSuccess) return;
        (void)hipGetLastError();   // clear sticky error, fall through to plain path
    }
    phA_k<<<dim3(MAXGRID), 256, 0, stream>>>(a);
    phB_k<<<dim3(MAXGRID), 256, 0, stream>>>(a);
    phC_k<<<dim3(MAXGRID), 256, 0, stream>>>(a);
    phD_k<<<dim3(MAXGRID), 256, 0, stream>>>(a);
    phE_k<<<dim3(MAXGRID), 256, 0, stream>>>(a);
    phF_k<<<dim3(MAXGRID), 256, 0, stream>>>(a);
}

// Round 12
// 118.922 us; speedup vs baseline: 1.1025x; 1.1025x over previous
//
#include <hip/hip_runtime.h>

// B=16,S=38 -> ROWS=608; D=1792; H=4, DK=448; NP=128; INF=768
typedef __attribute__((ext_vector_type(8))) short short8v;   // 8 bf16 (4 VGPR)
typedef __attribute__((ext_vector_type(4))) float f32x4;     // MFMA acc

#define APL 5120              // A plane stride (halfwords): 128*40
#define BPL 5184              // B plane stride: 128*40 + 8*8 (group pad)
#define BBASE 15360           // B region start (halfwords): 3*APL

struct MA {
    const float *X, *proto, *Wq, *bq, *Wk, *bk, *Wv, *bv, *Wo, *bo, *Wfc, *bfc, *Wqa, *bqa;
    float *Qp, *Kpart, *Q, *Kp, *WbigB, *WoQ, *WvWoQ, *cv, *const2, *out;
};

__device__ __forceinline__ float wave_sum(float v) {
    #pragma unroll
    for (int off = 32; off; off >>= 1) v += __shfl_down(v, off);
    return v;
}

// out[m*2+c] = A[m,:] @ W[:,c]  (W row-major [K][2]); K % 256 == 0
__device__ __forceinline__ void colvec2_unit(
    const float* __restrict__ A, int lda, const float* __restrict__ W,
    float* __restrict__ out, int K, int m, int lane)
{
    const float4* a = (const float4*)(A + (long)m * lda);
    float a0 = 0.f, a1 = 0.f;
    for (int i = 0; i < K / 256; ++i) {
        const int d4 = lane + 64 * i;
        float4 xv = a[d4];
        const float4* w = (const float4*)(W + (long)d4 * 8);
        float4 w0 = w[0], w1 = w[1];
        a0 += xv.x*w0.x + xv.y*w0.z + xv.z*w1.x + xv.w*w1.z;
        a1 += xv.x*w0.y + xv.y*w0.w + xv.z*w1.y + xv.w*w1.w;
    }
    a0 = wave_sum(a0); a1 = wave_sum(a1);
    if (lane == 0) { out[m * 2 + 0] = a0; out[m * 2 + 1] = a1; }
}

__device__ __forceinline__ void wvwoq_unit(
    const float* __restrict__ Wv, const float* __restrict__ WoQ,
    float* __restrict__ out, int d, int h, int lane)
{
    const float* wr = Wv + (long)d * 1792 + h * 448;
    const float* wq = WoQ + h * 448 * 2;
    float s0 = 0.f, s1 = 0.f;
    #pragma unroll
    for (int i = 0; i < 7; ++i) {
        const int j = lane + 64 * i;
        const float v = wr[j];
        s0 = fmaf(v, wq[j * 2 + 0], s0);
        s1 = fmaf(v, wq[j * 2 + 1], s1);
    }
    s0 = wave_sum(s0); s1 = wave_sum(s1);
    if (lane == 0) {
        out[((long)h * 1792 + d) * 2 + 0] = s0;
        out[((long)h * 1792 + d) * 2 + 1] = s1;
    }
}

__device__ __forceinline__ void bias_unit(
    const float* __restrict__ bv, const float* __restrict__ WoQ,
    const float* __restrict__ bfc, const float* __restrict__ Wqa,
    const float* __restrict__ bo, const float* __restrict__ WfbQ,
    const float* __restrict__ bqa,
    float* __restrict__ cv, float* __restrict__ const2, int unit, int lane)
{
    float s0 = 0.f, s1 = 0.f;
    if (unit < 4) {
        const int h = unit;
        #pragma unroll
        for (int i = 0; i < 7; ++i) {
            const int j = h * 448 + lane + 64 * i;
            const float v = bv[j];
            s0 = fmaf(v, WoQ[j * 2 + 0], s0);
            s1 = fmaf(v, WoQ[j * 2 + 1], s1);
        }
    } else {
        for (int k = lane; k < 1792; k += 64) {
            if (k < 768) {
                s0 = fmaf(bfc[k], Wqa[k * 2 + 0], s0);
                s1 = fmaf(bfc[k], Wqa[k * 2 + 1], s1);
            }
            s0 = fmaf(bo[k], WfbQ[k * 2 + 0], s0);
            s1 = fmaf(bo[k], WfbQ[k * 2 + 1], s1);
        }
    }
    s0 = wave_sum(s0); s1 = wave_sum(s1);
    if (lane == 0) {
        if (unit < 4) { cv[unit * 2 + 0] = s0; cv[unit * 2 + 1] = s1; }
        else          { const2[0] = s0 + bqa[0]; const2[1] = s1 + bqa[1]; }
    }
}

// fp32 -> 3 bf16 limbs (truncation; residue <= 2^-24 |f|)
__device__ __forceinline__ void split3(float f, unsigned& h, unsigned& m, unsigned& l) {
    unsigned u = __float_as_uint(f);
    h = u >> 16;
    float r1 = f - __uint_as_float(u & 0xFFFF0000u);
    unsigned u1 = __float_as_uint(r1);
    m = u1 >> 16;
    float r2 = r1 - __uint_as_float(u1 & 0xFFFF0000u);
    l = __float_as_uint(r2) >> 16;
}

__device__ __forceinline__ int BROWF(int n) { return n * 40 + (n >> 4) * 8; }

// bf16x3 MFMA GEMM tile (identical math/layout to round-9/11 verified kernel).
// 256 threads = 4 waves (2x2 of 64x64), 128x128 tile, K-step 32, single-buffer LDS.
template<bool TRANSB>
__device__ void gemm_tile(unsigned short* sh,
    const float* __restrict__ A, int lda,
    const float* __restrict__ B, int ldb,
    float* __restrict__ Cslab, int M, int N,
    int rowBase, int colBase, int kbeg, int nsteps)
{
    const int tid = threadIdx.x;
    const int lane = tid & 63, wave = tid >> 6;
    const int g = lane >> 4, c = lane & 15;
    const int wm = (wave >> 1) * 64, wn = (wave & 1) * 64;

    const int s_arow = tid >> 1, s_ak = (tid & 1) * 16;
    const int s_bk = tid >> 3,  s_bn = (tid & 7) * 16;
    const int s_tn = tid >> 1,  s_tk = (tid & 1) * 16;

    const bool aok = (rowBase + s_arow) < M;
    const float* Arow = A + (long)(rowBase + s_arow) * lda;

    float4 ra[4], rb[4];
    auto loadRaw = [&](int ks) {
        const int k0 = kbeg + ks * 32;
        #pragma unroll
        for (int i = 0; i < 4; ++i)
            ra[i] = aok ? *(const float4*)&Arow[k0 + s_ak + i * 4]
                        : make_float4(0.f, 0.f, 0.f, 0.f);
        if (!TRANSB) {
            const float* bp = B + (long)(k0 + s_bk) * ldb + colBase + s_bn;
            #pragma unroll
            for (int i = 0; i < 4; ++i) rb[i] = *(const float4*)&bp[i * 4];
        } else {
            const float* bp = B + (long)(colBase + s_tn) * ldb + k0 + s_tk;
            #pragma unroll
            for (int i = 0; i < 4; ++i) rb[i] = *(const float4*)&bp[i * 4];
        }
    };

    auto stageWrite = [&]() {
        {
            const float* f = (const float*)ra;
            unsigned ph[8], pm[8], pl[8];
            #pragma unroll
            for (int j = 0; j < 8; ++j) {
                unsigned h0, m0, l0, h1, m1, l1;
                split3(f[2*j], h0, m0, l0);
                split3(f[2*j+1], h1, m1, l1);
                ph[j] = h0 | (h1 << 16);
                pm[j] = m0 | (m1 << 16);
                pl[j] = l0 | (l1 << 16);
            }
            const int base = s_arow * 40 + s_ak;
            unsigned short* ap = sh;
            *(uint4*)&ap[0*APL + base]     = make_uint4(ph[0],ph[1],ph[2],ph[3]);
            *(uint4*)&ap[0*APL + base + 8] = make_uint4(ph[4],ph[5],ph[6],ph[7]);
            *(uint4*)&ap[1*APL + base]     = make_uint4(pm[0],pm[1],pm[2],pm[3]);
            *(uint4*)&ap[1*APL + base + 8] = make_uint4(pm[4],pm[5],pm[6],pm[7]);
            *(uint4*)&ap[2*APL + base]     = make_uint4(pl[0],pl[1],pl[2],pl[3]);
            *(uint4*)&ap[2*APL + base + 8] = make_uint4(pl[4],pl[5],pl[6],pl[7]);
        }
        unsigned short* bp = sh + BBASE;
        if (!TRANSB) {
            const float* f = (const float*)rb;
            #pragma unroll
            for (int j = 0; j < 16; ++j) {
                unsigned h, m, l;
                split3(f[j], h, m, l);
                const int ad = BROWF(s_bn + j) + s_bk;
                bp[0*BPL + ad] = (unsigned short)h;
                bp[1*BPL + ad] = (unsigned short)m;
                bp[2*BPL + ad] = (unsigned short)l;
            }
        } else {
            const float* f = (const float*)rb;
            unsigned ph[8], pm[8], pl[8];
            #pragma unroll
            for (int j = 0; j < 8; ++j) {
                unsigned h0, m0, l0, h1, m1, l1;
                split3(f[2*j], h0, m0, l0);
                split3(f[2*j+1], h1, m1, l1);
                ph[j] = h0 | (h1 << 16);
                pm[j] = m0 | (m1 << 16);
                pl[j] = l0 | (l1 << 16);
            }
            const int base = BROWF(s_tn) + s_tk;
            *(uint4*)&bp[0*BPL + base]     = make_uint4(ph[0],ph[1],ph[2],ph[3]);
            *(uint4*)&bp[0*BPL + base + 8] = make_uint4(ph[4],ph[5],ph[6],ph[7]);
            *(uint4*)&bp[1*BPL + base]     = make_uint4(pm[0],pm[1],pm[2],pm[3]);
            *(uint4*)&bp[1*BPL + base + 8] = make_uint4(pm[4],pm[5],pm[6],pm[7]);
            *(uint4*)&bp[2*BPL + base]     = make_uint4(pl[0],pl[1],pl[2],pl[3]);
            *(uint4*)&bp[2*BPL + base + 8] = make_uint4(pl[4],pl[5],pl[6],pl[7]);
        }
    };

    f32x4 acc[4][4];
    #pragma unroll
    for (int i = 0; i < 4; ++i)
        #pragma unroll
        for (int j = 0; j < 4; ++j)
            acc[i][j] = (f32x4){0.f, 0.f, 0.f, 0.f};

    loadRaw(0);
    for (int s = 0; s < nsteps; ++s) {
        __syncthreads();
        stageWrite();
        if (s + 1 < nsteps) loadRaw(s + 1);
        __syncthreads();

        const unsigned short* ap = sh;
        const unsigned short* bp = sh + BBASE;
        short8v bfr[3][4];
        #pragma unroll
        for (int ni = 0; ni < 4; ++ni) {
            const int hwb = (wn + 16*ni + c) * 40 + ((wn + 16*ni) >> 4) * 8 + 8 * g;
            bfr[0][ni] = *(const short8v*)&bp[0*BPL + hwb];
            bfr[1][ni] = *(const short8v*)&bp[1*BPL + hwb];
            bfr[2][ni] = *(const short8v*)&bp[2*BPL + hwb];
        }
        #pragma unroll
        for (int mi = 0; mi < 4; ++mi) {
            const int hwa = (wm + 16*mi + c) * 40 + 8 * g;
            short8v ah = *(const short8v*)&ap[0*APL + hwa];
            short8v am = *(const short8v*)&ap[1*APL + hwa];
            short8v al = *(const short8v*)&ap[2*APL + hwa];
            #pragma unroll
            for (int ni = 0; ni < 4; ++ni) {
                f32x4 t = acc[mi][ni];
                t = __builtin_amdgcn_mfma_f32_16x16x32_bf16(ah, bfr[0][ni], t, 0, 0, 0);
                t = __builtin_amdgcn_mfma_f32_16x16x32_bf16(ah, bfr[1][ni], t, 0, 0, 0);
                t = __builtin_amdgcn_mfma_f32_16x16x32_bf16(am, bfr[0][ni], t, 0, 0, 0);
                t = __builtin_amdgcn_mfma_f32_16x16x32_bf16(ah, bfr[2][ni], t, 0, 0, 0);
                t = __builtin_amdgcn_mfma_f32_16x16x32_bf16(am, bfr[1][ni], t, 0, 0, 0);
                t = __builtin_amdgcn_mfma_f32_16x16x32_bf16(al, bfr[0][ni], t, 0, 0, 0);
                acc[mi][ni] = t;
            }
        }
    }

    #pragma unroll
    for (int mi = 0; mi < 4; ++mi)
        #pragma unroll
        for (int ni = 0; ni < 4; ++ni) {
            const int col = colBase + wn + 16*ni + c;
            #pragma unroll
            for (int r = 0; r < 4; ++r) {
                const int row = rowBase + wm + 16*mi + 4*g + r;
                if (row < M) Cslab[(long)row * N + col] = acc[mi][ni][r];
            }
        }
}

// ---- K1: Q partials (split 4) + Kp partials (split 14) + WbigB = Wfc@Wqa ----
__global__ __launch_bounds__(256) void k1(MA a) {
    __shared__ unsigned short sh[30912];
    const int w = blockIdx.x;
    const int lane = threadIdx.x & 63, wave = threadIdx.x >> 6;
    if (w < 280) {
        // Q = X @ Wq : slab kb (0..3), tiles 5x14
        const int kb = w / 70, r = w % 70, my = r / 14, nx = r % 14;
        gemm_tile<false>(sh, a.X, 1792, a.Wq, 1792,
                         a.Qp + (long)kb * 1089536, 608, 1792,
                         my * 128, nx * 128, kb * 448, 14);
    } else if (w < 476) {
        // Kp = proto @ Wk : slab kb (0..13), tiles 1x14
        const int t = w - 280, kb = t / 14, nx = t % 14;
        gemm_tile<false>(sh, a.proto, 1792, a.Wk, 1792,
                         a.Kpart + (long)kb * 229376, 128, 1792,
                         0, nx * 128, kb * 128, 4);
    } else {
        // WbigB (Wbig rows 0..1791, WfbQ rows 1792..3583)
        const int u = (w - 476) * 4 + wave;
        if (u < 3584) colvec2_unit(a.Wfc, 768, a.Wqa, a.WbigB, 768, u, lane);
    }
}

// ---- K2: reduce Q(+bq), reduce Kp(+bk), WoQ = Wo @ WfbQ ----
__global__ __launch_bounds__(256) void k2(MA a) {
    const int w = blockIdx.x;
    const int lane = threadIdx.x & 63, wave = threadIdx.x >> 6;
    if (w < 1064) {
        const long i0 = (long)w * 1024 + threadIdx.x * 4;    // < 1,089,536
        float4 s = make_float4(0.f, 0.f, 0.f, 0.f);
        #pragma unroll
        for (int z = 0; z < 4; ++z) {
            float4 v = *(const float4*)&a.Qp[z * 1089536L + i0];
            s.x += v.x; s.y += v.y; s.z += v.z; s.w += v.w;
        }
        const int col = (int)(i0 % 1792);
        float4 b4 = *(const float4*)&a.bq[col];
        s.x += b4.x; s.y += b4.y; s.z += b4.z; s.w += b4.w;
        *(float4*)&a.Q[i0] = s;
    } else if (w < 1288) {
        const long i0 = (long)(w - 1064) * 1024 + threadIdx.x * 4;  // < 229,376
        float4 s = make_float4(0.f, 0.f, 0.f, 0.f);
        for (int z = 0; z < 14; ++z) {
            float4 v = *(const float4*)&a.Kpart[z * 229376L + i0];
            s.x += v.x; s.y += v.y; s.z += v.z; s.w += v.w;
        }
        const int col = (int)(i0 % 1792);
        float4 b4 = *(const float4*)&a.bk[col];
        s.x += b4.x; s.y += b4.y; s.z += b4.z; s.w += b4.w;
        *(float4*)&a.Kp[i0] = s;
    } else {
        const int u = (w - 1288) * 4 + wave;
        if (u < 1792) colvec2_unit(a.Wo, 1792, a.WbigB + 3584, a.WoQ, 1792, u, lane);
    }
}

// ---- K3: Sc_h = Q_h @ Kp_h^T (split 7) + wvwoq + bias ----
__global__ __launch_bounds__(256) void k3(MA a) {
    __shared__ unsigned short sh[30912];
    const int w = blockIdx.x;
    const int lane = threadIdx.x & 63, wave = threadIdx.x >> 6;
    if (w < 140) {
        const int kb = w / 20, r = w % 20, my = r / 4, h = r % 4;
        gemm_tile<true>(sh, a.Q + h * 448, 1792, a.Kp + h * 448, 1792,
                        a.Qp + (long)(kb * 4 + h) * 77824, 608, 128,
                        my * 128, 0, kb * 64, 2);
    } else if (w < 1932) {
        const int u = (w - 140) * 4 + wave;
        if (u < 7168) wvwoq_unit(a.Wv, a.WoQ, a.WvWoQ, u % 1792, u / 1792, lane);
    } else {
        const int u = (w - 1932) * 4 + wave;
        if (u < 5) bias_unit(a.bv, a.WoQ, a.bfc, a.Wqa, a.bo, a.WbigB + 3584,
                             a.bqa, a.cv, a.const2, u, lane);
    }
}

// ---- K4: per-(row,head) argmax over 7 slabs + final logits ----
__global__ __launch_bounds__(256) void k4(MA a) {
    const int lane = threadIdx.x & 63, wave = threadIdx.x >> 6;
    const int row = blockIdx.x * 4 + wave;          // 152*4 == 608
    if (row >= 608) return;

    int sel[4];
    #pragma unroll
    for (int h = 0; h < 4; ++h) {
        float s0 = 0.f, s1 = 0.f;
        #pragma unroll
        for (int z = 0; z < 7; ++z) {
            const long base = ((long)(z * 4 + h) * 608 + row) * 128;
            s0 += a.Qp[base + lane];
            s1 += a.Qp[base + lane + 64];
        }
        float best = s0; int bi = lane;
        if (s1 > best) { best = s1; bi = lane + 64; }
        #pragma unroll
        for (int off = 32; off; off >>= 1) {
            float ov = __shfl_down(best, off);
            int   oi = __shfl_down(bi, off);
            if (ov > best || (ov == best && oi < bi)) { best = ov; bi = oi; }
        }
        sel[h] = __shfl(bi, 0);
    }

    float a0 = 0.f, a1 = 0.f;
    auto dot2 = [&](const float* av_, const float* w_) {
        const float4* av = (const float4*)av_;
        #pragma unroll
        for (int i = 0; i < 7; ++i) {
            const int d4 = lane + 64 * i;
            float4 xv = av[d4];
            const float4* wp = (const float4*)(w_ + (long)d4 * 8);
            float4 w0 = wp[0], w1 = wp[1];
            a0 += xv.x*w0.x + xv.y*w0.z + xv.z*w1.x + xv.w*w1.z;
            a1 += xv.x*w0.y + xv.y*w0.w + xv.z*w1.y + xv.w*w1.w;
        }
    };
    dot2(a.X + (long)row * 1792, a.WbigB);
    #pragma unroll
    for (int h = 0; h < 4; ++h)
        dot2(a.proto + (long)sel[h] * 1792, a.WvWoQ + (long)h * 3584);

    a0 = wave_sum(a0); a1 = wave_sum(a1);
    if (lane == 0) {
        a.out[row * 2 + 0] = a0 + a.const2[0] + a.cv[0] + a.cv[2] + a.cv[4] + a.cv[6];
        a.out[row * 2 + 1] = a1 + a.const2[1] + a.cv[1] + a.cv[3] + a.cv[5] + a.cv[7];
    }
}

extern "C" void kernel_launch(void* const* d_in, const int* in_sizes, int n_in,
                              void* d_out, int out_size, void* d_ws, size_t ws_size,
                              hipStream_t stream)
{
    MA a;
    a.X     = (const float*)d_in[0];
    a.proto = (const float*)d_in[1];
    a.Wq  = (const float*)d_in[3];
    a.bq  = (const float*)d_in[4];
    a.Wk  = (const float*)d_in[5];
    a.bk  = (const float*)d_in[6];
    a.Wv  = (const float*)d_in[7];
    a.bv  = (const float*)d_in[8];
    a.Wo  = (const float*)d_in[9];
    a.bo  = (const float*)d_in[10];
    a.Wfc = (const float*)d_in[11];
    a.bfc = (const float*)d_in[12];
    a.Wqa = (const float*)d_in[13];
    a.bqa = (const float*)d_in[14];
    a.out = (float*)d_out;

    float* ws = (float*)d_ws;
    a.Qp     = ws;                      // 4,358,144 (Q partials; reused as Sc partials in K3/K4)
    a.Kpart  = a.Qp + 4358144;          // 3,211,264 (Kp partials, 14 slabs)
    a.Q      = a.Kpart + 3211264;       // 1,089,536 [608][1792]
    a.Kp     = a.Q + 1089536;           // 229,376   [128][1792]
    a.WbigB  = a.Kp + 229376;           // 7,168     [3584][2] (top=Wbig, bottom=WfbQ)
    a.WoQ    = a.WbigB + 7168;          // 3,584     [1792][2]
    a.WvWoQ  = a.WoQ + 3584;            // 14,336    [4][1792][2]
    a.cv     = a.WvWoQ + 14336;         // 8
    a.const2 = a.cv + 8;                // 2 (+6 pad)

    k1<<<dim3(476 + 896), 256, 0, stream>>>(a);
    k2<<<dim3(1288 + 448), 256, 0, stream>>>(a);
    k3<<<dim3(140 + 1792 + 2), 256, 0, stream>>>(a);
    k4<<<dim3(152), 256, 0, stream>>>(a);
}